// Round 16
// baseline (141.429 us; speedup 1.0000x reference)
//
#include <hip/hip_runtime.h>
#include <hip/hip_bf16.h>

// MoE MLP top-1 + shared expert. T=2048 H=768 I=2048 E=8, f32 in/out.
// R16 = R15 (137us) + stageB split-K (grid (6,40,2), 32 chunks/block,
//       atomicAdd both halves) + stageB launch_bounds(256,4).
//   K1: gate/up conv blocks + router tail (no global atomics).
//   plan: 1-block histogram/segments/list/loss (LDS atomics).
//   K2 = stageA + down conv fused; K3 = stageB. Layout (e,nt,kc).
// Chunk = 128 n x 32 k bf16 (4096 u16 = 8KB), in-chunk addr:
//   ((n>>4)&7)*512 + ((k>>3)&3)*128 + (n&15)*8 + (k&7)
// gll16 copies chunks linearly in the GEMMs; fragment reads linear-in-lane.

#define TT 2048
#define HH 768
#define II 2048
#define NE 8
#define RSLOTS 3072   // routed padded slots (24 tiles of 128)
#define LDSW 138      // wconv LDS row stride (u16)
#define GUCH 6912     // gate/up chunks (9 x {g,u} x 24 kc x 16 nt)
#define RBLK 512      // router blocks (tail of K1's grid)
#define SABLK 640     // stageA blocks (16 nt x 40 mty)
#define DCH 3456      // down chunks (9 x 64 kc x 6 nt)

typedef unsigned short u16;
typedef unsigned int u32;
typedef short s16x8 __attribute__((ext_vector_type(8)));
typedef u16 u16x8 __attribute__((ext_vector_type(8)));
typedef float f32x4 __attribute__((ext_vector_type(4)));

__device__ __forceinline__ u16 f2bf(float f) {  // f32 -> bf16 RNE
  u32 u = __builtin_bit_cast(u32, f);
  return (u16)((u + 0x7FFFu + ((u >> 16) & 1u)) >> 16);
}

typedef __attribute__((address_space(3))) u32 lds_u32;
typedef const __attribute__((address_space(1))) u32 glb_u32;
__device__ __forceinline__ void gll16(const void* g, void* l) {
  // global src per-lane; LDS dest wave-uniform base + lane*16 (linear)
  __builtin_amdgcn_global_load_lds((glb_u32*)g,
                                   (lds_u32*)(u32)(unsigned long long)l, 16, 0, 0);
}

// R5 one-shot conv body: [32k x 128n] f32 (row stride N) -> one tiled chunk.
__device__ __forceinline__ void conv_chunk(const float* src, int N, int k0, int n0,
                                           u16* dst, u16* lds, int t) {
  // phase 1: coalesced f32x4 reads along n; bf16 rows into LDS
  {
    const int k = t >> 3;         // 0..31
    const int nb = (t & 7) * 16;  // 16 consecutive n per thread
    const float* rp = src + (size_t)(k0 + k) * N + n0 + nb;
    const f32x4 a0 = *reinterpret_cast<const f32x4*>(rp);
    const f32x4 a1 = *reinterpret_cast<const f32x4*>(rp + 4);
    const f32x4 a2 = *reinterpret_cast<const f32x4*>(rp + 8);
    const f32x4 a3 = *reinterpret_cast<const f32x4*>(rp + 12);
    u16x8 w0, w1;
#pragma unroll
    for (int j = 0; j < 4; ++j) {
      w0[j] = f2bf(a0[j]); w0[j + 4] = f2bf(a1[j]);
      w1[j] = f2bf(a2[j]); w1[j + 4] = f2bf(a3[j]);
    }
    *reinterpret_cast<u16x8*>(&lds[k * LDSW + nb]) = w0;
    *reinterpret_cast<u16x8*>(&lds[k * LDSW + nb + 8]) = w1;
  }
  __syncthreads();
  // phase 2: k-minor gather from LDS, coalesced u16x8 stores
#pragma unroll
  for (int r = 0; r < 2; ++r) {
    const int o = t + r * 256;  // 0..511
    const int fr = o & 15, fq = (o >> 4) & 3, nq = o >> 6;
    u16x8 w;
#pragma unroll
    for (int j = 0; j < 8; ++j) w[j] = lds[(fq * 8 + j) * LDSW + nq * 16 + fr];
    *reinterpret_cast<u16x8*>(&dst[o * 8]) = w;
  }
}

// ---------------- K1: gate/up conversion + router (no atomics) ----------------
// blocks [0,GUCH): gu chunks, id: m=id/384 (e=m>>1, mat=m&1), r=id%384,
//   kc=r>>4, nt=r&15. dst (e,nt,kc): chunk ((e*16+nt)*24+kc).
// blocks [GUCH,GUCH+RBLK): router, one wave per token -> best[], score[].
__global__ __launch_bounds__(256) void guconv_router_kernel(
    const float* __restrict__ gate_w, const float* __restrict__ up_w,
    const float* __restrict__ sh_gate, const float* __restrict__ sh_up,
    u16* __restrict__ Wgt, u16* __restrict__ Wut,
    const float* __restrict__ x, const float* __restrict__ rw,
    float* __restrict__ score, int* __restrict__ best_g) {
  __shared__ u16 lds[32 * LDSW];  // 8.8 KB
  const int t = threadIdx.x;

  if (blockIdx.x >= GUCH) {
    // ---- router: one wave per token; plain stores only ----
    const int tok = (int)(((blockIdx.x - GUCH) * 256 + t) >> 6);
    const int lane = t & 63;
    if (tok >= TT) return;
    double acc[NE];
#pragma unroll
    for (int e = 0; e < NE; ++e) acc[e] = 0.0;
    const float* xr = x + (size_t)tok * HH;
    for (int h = lane; h < HH; h += 64) {
      const double xv = (double)xr[h];
#pragma unroll
      for (int e = 0; e < NE; ++e) acc[e] += xv * (double)rw[h * NE + e];
    }
#pragma unroll
    for (int off = 32; off > 0; off >>= 1) {
#pragma unroll
      for (int e = 0; e < NE; ++e) acc[e] += __shfl_xor(acc[e], off);
    }
    if (lane == 0) {
      int best = 0;
#pragma unroll
      for (int e = 1; e < NE; ++e)
        if (acc[e] > acc[best]) best = e;  // strict > == first-max (jnp.argmax)
      score[tok] = 1.0f / (1.0f + __expf((float)(-acc[best])));
      best_g[tok] = best;
    }
    return;
  }

  const int id = blockIdx.x;  // [0, GUCH)
  const int m = id / 384, r = id % 384;
  const int e = m >> 1;
  const int kc = r >> 4, nt = r & 15;
  const float* src = (m & 1) ? (e < 8 ? up_w + (size_t)e * HH * II : sh_up)
                             : (e < 8 ? gate_w + (size_t)e * HH * II : sh_gate);
  u16* dst = ((m & 1) ? Wut : Wgt) + ((size_t)(e * 16 + nt) * 24 + kc) * 4096;
  conv_chunk(src, II, kc * 32, nt * 128, dst, lds, t);
}

// ---------------- plan: histogram + segments + list + loss (1 block) ----------------
__global__ __launch_bounds__(256) void plan_kernel(
    const int* __restrict__ best_g, const float* __restrict__ score,
    int* __restrict__ cnt, int* __restrict__ list, int* __restrict__ meta,
    float* __restrict__ out) {
  __shared__ int hist[NE], cursor[NE];
  __shared__ float psum[NE];
  const int t = threadIdx.x;
  if (t < NE) {
    hist[t] = 0;
    cursor[t] = 0;
    psum[t] = 0.0f;
  }
  __syncthreads();
  // pass 1: histogram + prob sums (LDS atomics)
#pragma unroll
  for (int i = 0; i < TT / 256; ++i) {
    const int tok = t + i * 256;
    const int e = best_g[tok];
    atomicAdd(&hist[e], 1);
    atomicAdd(&psum[e], score[tok]);
  }
  __syncthreads();
  if (t == 0) {
    int S = 0;
    float s = 0.0f;
    for (int e = 0; e < NE; ++e) {
      cnt[e] = hist[e];
      meta[e] = S;
      const int pad = (hist[e] + 127) & ~127;
      for (int tl = S >> 7; tl < (S + pad) >> 7; ++tl) meta[16 + tl] = e;
      S += pad;
      s += (float)hist[e] * psum[e];
    }
    meta[8] = S;
    for (int tl = S >> 7; tl < 24; ++tl) meta[16 + tl] = 0;
    out[(size_t)TT * HH] = s * (0.001f * (float)NE / ((float)TT * (float)TT));
  }
  __syncthreads();
  // pass 2: compacted per-expert lists (LDS cursors; order irrelevant)
#pragma unroll
  for (int i = 0; i < TT / 256; ++i) {
    const int tok = t + i * 256;
    const int e = best_g[tok];
    const int pos = atomicAdd(&cursor[e], 1);
    list[e * TT + pos] = tok;
  }
}

// ---------------- gather: x -> tiled bf16 Xc (+tokmap) ----------------
__global__ __launch_bounds__(256) void gather_kernel(
    const float* __restrict__ x, const float* __restrict__ score,
    const int* __restrict__ list, const int* __restrict__ cnt,
    const int* __restrict__ meta, u16* __restrict__ Xc, int* __restrict__ tokmap) {
  const int task = blockIdx.x * 4 + (threadIdx.x >> 6);
  const int lane = threadIdx.x & 63;
  const int pb = task / 24;  // 16-row block, 0..319
  const int c = task % 24;   // k chunk
  const int fq = lane >> 4, fr = lane & 15;
  const int p = pb * 16 + fr;
  int tok;
  float sc;
  if (p >= RSLOTS) {
    tok = p - RSLOTS;
    sc = 1.0f;
  } else {
    const int e = meta[16 + (p >> 7)];
    const int idx = p - meta[e];
    tok = (idx >= 0 && idx < cnt[e]) ? list[e * TT + idx] : -1;
    sc = (tok >= 0) ? score[tok] : 0.0f;
  }
  u16x8 w = {0, 0, 0, 0, 0, 0, 0, 0};
  if (tok >= 0) {
    const float* xp = x + (size_t)tok * HH + c * 32 + fq * 8;
    const f32x4 a = *reinterpret_cast<const f32x4*>(xp);
    const f32x4 b = *reinterpret_cast<const f32x4*>(xp + 4);
#pragma unroll
    for (int j = 0; j < 4; ++j) {
      w[j] = f2bf(a[j] * sc);
      w[j + 4] = f2bf(b[j] * sc);
    }
  }
  *reinterpret_cast<u16x8*>(&Xc[((size_t)(pb >> 3) * 24 + c) * 4096 + (pb & 7) * 512 +
                                lane * 8]) = w;
  if (c == 0 && fq == 0) tokmap[p] = tok;
}

// ---------------- K2: stageA + down conversion fused ----------------
// blocks [0,SABLK): stageA (nt=b&15, mty=b>>4; mty<24 routed, >=24 shared).
// blocks [SABLK,SABLK+DCH): down chunks, id: e=id/384, r=id%384, kc=r/6, nt=r%6.
// dst (e,nt,kc): chunk ((e*6+nt)*64+kc). Wdt consumed by stageB.
__global__ __launch_bounds__(256, 3) void stageA_dconv_kernel(
    const u16* __restrict__ Xc, const int* __restrict__ meta,
    const u16* __restrict__ Wgt, const u16* __restrict__ Wut, u16* __restrict__ P,
    const float* __restrict__ down_w, const float* __restrict__ sh_down,
    u16* __restrict__ Wdt) {
  __shared__ char smem[49152];  // stageA: 48 KB; down conv: first 8.8 KB
  const int tid = threadIdx.x;

  if (blockIdx.x >= SABLK) {
    // ---- down conversion (R5 body) ----
    const int id = blockIdx.x - SABLK;  // [0, DCH)
    const int e = id / 384, r = id % 384;
    const int kc = r / 6, nt = r % 6;
    const float* src = (e < 8) ? down_w + (size_t)e * II * HH : sh_down;
    u16* dst = Wdt + ((size_t)(e * 6 + nt) * 64 + kc) * 4096;
    conv_chunk(src, HH, kc * 32, nt * 128, dst, (u16*)smem, tid);
    return;
  }

  // ---- stageA: P = silu(Xc Wg) * (Xc Wu) ----
  const int nt = blockIdx.x & 15, mty = blockIdx.x >> 4;
  int e;
  if (mty < 24) {
    if (mty * 128 >= meta[8]) return;
    e = meta[16 + mty];
  } else {
    e = 8;
  }
  const u16* wg = Wgt + (size_t)(e * 16 + nt) * 24 * 4096;
  const u16* wu = Wut + (size_t)(e * 16 + nt) * 24 * 4096;
  const u16* xa = Xc + (size_t)mty * 24 * 4096;

  u16(*As)[4096] = (u16(*)[4096])smem;
  u16(*Bgs)[4096] = (u16(*)[4096])(smem + 16384);
  u16(*Bus)[4096] = (u16(*)[4096])(smem + 32768);

  const int lane = tid & 63, wid = tid >> 6;
  const int fr = lane & 15, fq = lane >> 4;
  const int wm4 = (wid >> 1) * 4;  // row 16-block base
  const int wn4 = (wid & 1) * 4;   // col 16-block base
  const int wn = (wid & 1) * 64;
  const int ncol = nt * 128;
  const int so = wid * 1024 + lane * 8;  // gll global src offset (u16)
  const int sl = wid * 1024;             // gll LDS dst offset (u16), wave-uniform

  f32x4 accg[4][4], accu[4][4];
#pragma unroll
  for (int i = 0; i < 4; ++i)
#pragma unroll
    for (int j = 0; j < 4; ++j) {
      accg[i][j] = f32x4{0.f, 0.f, 0.f, 0.f};
      accu[i][j] = f32x4{0.f, 0.f, 0.f, 0.f};
    }

  // full chunk = 4096 u16; 4 waves x 2 gll16 x 512 u16 each
#define STAGE(c, buf)                                               \
  {                                                                 \
    gll16(xa + (size_t)(c) * 4096 + so, &As[buf][sl]);              \
    gll16(xa + (size_t)(c) * 4096 + so + 512, &As[buf][sl + 512]);  \
    gll16(wg + (size_t)(c) * 4096 + so, &Bgs[buf][sl]);             \
    gll16(wg + (size_t)(c) * 4096 + so + 512, &Bgs[buf][sl + 512]); \
    gll16(wu + (size_t)(c) * 4096 + so, &Bus[buf][sl]);             \
    gll16(wu + (size_t)(c) * 4096 + so + 512, &Bus[buf][sl + 512]); \
  }

  STAGE(0, 0)
  __syncthreads();
  int cur = 0;
  for (int c = 0; c < 24; ++c) {
    if (c < 23) STAGE(c + 1, cur ^ 1)
    s16x8 af[4], bg[4], bu[4];
#pragma unroll
    for (int i = 0; i < 4; ++i) {
      af[i] = *reinterpret_cast<const s16x8*>(&As[cur][(wm4 + i) * 512 + fq * 128 + fr * 8]);
      bg[i] = *reinterpret_cast<const s16x8*>(&Bgs[cur][(wn4 + i) * 512 + fq * 128 + fr * 8]);
      bu[i] = *reinterpret_cast<const s16x8*>(&Bus[cur][(wn4 + i) * 512 + fq * 128 + fr * 8]);
    }
#pragma unroll
    for (int j = 0; j < 4; ++j)
#pragma unroll
      for (int i = 0; i < 4; ++i) {
        accg[i][j] = __builtin_amdgcn_mfma_f32_16x16x32_bf16(af[i], bg[j], accg[i][j], 0, 0, 0);
        accu[i][j] = __builtin_amdgcn_mfma_f32_16x16x32_bf16(af[i], bu[j], accu[i][j], 0, 0, 0);
      }
    __syncthreads();
    cur ^= 1;
  }
#undef STAGE

  // epilogue: silu(g)*u -> P tiled bf16 (C/D: row=fq*4+reg, col=fr)
#pragma unroll
  for (int i = 0; i < 4; ++i)
#pragma unroll
    for (int cc = 0; cc < 4; ++cc) {
      const int rlo = fq * 4 + cc;  // row & 15 within 16-block (wm4+i)
#pragma unroll
      for (int j = 0; j < 4; ++j) {
        const int k = ncol + wn + j * 16 + fr;  // global i-col
        const float gv = accg[i][j][cc];
        const float val = (gv / (1.0f + __expf(-gv))) * accu[i][j][cc];
        P[((size_t)mty * 64 + (k >> 5)) * 4096 + (size_t)(wm4 + i) * 512 +
          ((k >> 3) & 3) * 128 + rlo * 8 + (k & 7)] = f2bf(val);
      }
    }
}

// ---------------- stage B: out += P Wd (atomicAdd, out pre-zeroed) ----------------
// grid (6 nt, 40 mty, 2 kh): split-K, 32 chunks per block; each out element
// gets one shared + at most one routed contribution per k-half (all atomic).
__global__ __launch_bounds__(256, 4) void stageB_kernel(
    const u16* __restrict__ P, const int* __restrict__ meta,
    const int* __restrict__ tokmap, const u16* __restrict__ Wdt,
    float* __restrict__ out) {
  const int mty = blockIdx.y, nt = blockIdx.x, kh = blockIdx.z;
  int e;
  if (mty < 24) {
    if (mty * 128 >= meta[8]) return;
    e = meta[16 + mty];
  } else {
    e = 8;
  }
  const u16* wd = Wdt + ((size_t)(e * 6 + nt) * 64 + kh * 32) * 4096;
  const u16* pa = P + ((size_t)mty * 64 + kh * 32) * 4096;

  __shared__ u16 As[2][4096], Bs[2][4096];

  const int tid = threadIdx.x, lane = tid & 63, wid = tid >> 6;
  const int fr = lane & 15, fq = lane >> 4;
  const int wm4 = (wid >> 1) * 4;
  const int wn4 = (wid & 1) * 4;
  const int wm = (wid >> 1) * 64;
  const int wn = (wid & 1) * 64;
  const int ncol = nt * 128;
  const int so = wid * 1024 + lane * 8;
  const int sl = wid * 1024;

  f32x4 acc[4][4];
#pragma unroll
  for (int i = 0; i < 4; ++i)
#pragma unroll
    for (int j = 0; j < 4; ++j) acc[i][j] = f32x4{0.f, 0.f, 0.f, 0.f};

#define STAGEB(c, buf)                                              \
  {                                                                 \
    gll16(pa + (size_t)(c) * 4096 + so, &As[buf][sl]);              \
    gll16(pa + (size_t)(c) * 4096 + so + 512, &As[buf][sl + 512]);  \
    gll16(wd + (size_t)(c) * 4096 + so, &Bs[buf][sl]);              \
    gll16(wd + (size_t)(c) * 4096 + so + 512, &Bs[buf][sl + 512]);  \
  }

  STAGEB(0, 0)
  __syncthreads();
  int cur = 0;
  for (int c = 0; c < 32; ++c) {
    if (c < 31) STAGEB(c + 1, cur ^ 1)
    s16x8 af[4], bf[4];
#pragma unroll
    for (int i = 0; i < 4; ++i) {
      af[i] = *reinterpret_cast<const s16x8*>(&As[cur][(wm4 + i) * 512 + fq * 128 + fr * 8]);
      bf[i] = *reinterpret_cast<const s16x8*>(&Bs[cur][(wn4 + i) * 512 + fq * 128 + fr * 8]);
    }
#pragma unroll
    for (int j = 0; j < 4; ++j)
#pragma unroll
      for (int i = 0; i < 4; ++i)
        acc[i][j] = __builtin_amdgcn_mfma_f32_16x16x32_bf16(af[i], bf[j], acc[i][j], 0, 0, 0);
    __syncthreads();
    cur ^= 1;
  }
#undef STAGEB

#pragma unroll
  for (int i = 0; i < 4; ++i)
#pragma unroll
    for (int cc = 0; cc < 4; ++cc) {
      const int p = mty * 128 + wm + i * 16 + fq * 4 + cc;
      const int tok = tokmap[p];
      if (tok >= 0) {
#pragma unroll
        for (int j = 0; j < 4; ++j)
          atomicAdd(&out[(size_t)tok * HH + ncol + wn + j * 16 + fr], acc[i][j][cc]);
      }
    }
}

// ---------------- launcher ----------------
extern "C" void kernel_launch(void* const* d_in, const int* in_sizes, int n_in,
                              void* d_out, int out_size, void* d_ws, size_t ws_size,
                              hipStream_t stream) {
  (void)in_sizes; (void)n_in; (void)ws_size;
  const float* x = (const float*)d_in[0];
  const float* rw = (const float*)d_in[1];
  const float* gate_w = (const float*)d_in[2];
  const float* up_w = (const float*)d_in[3];
  const float* down_w = (const float*)d_in[4];
  const float* sh_gate = (const float*)d_in[5];
  const float* sh_up = (const float*)d_in[6];
  const float* sh_down = (const float*)d_in[7];
  float* out = (float*)d_out;

  char* ws = (char*)d_ws;
  size_t off = 0;
  u16* Xc = (u16*)(ws + off);  off += (size_t)(RSLOTS + TT) * HH * sizeof(u16);   // 7.9MB
  u16* P = (u16*)(ws + off);   off += (size_t)(RSLOTS + TT) * II * sizeof(u16);   // 21MB
  u16* Wgt = (u16*)(ws + off); off += (size_t)9 * 16 * 24 * 4096 * sizeof(u16);   // 28.3MB
  u16* Wut = (u16*)(ws + off); off += (size_t)9 * 16 * 24 * 4096 * sizeof(u16);   // 28.3MB
  u16* Wdt = (u16*)(ws + off); off += (size_t)9 * 6 * 64 * 4096 * sizeof(u16);    // 28.3MB
  float* score = (float*)(ws + off);   off += TT * sizeof(float);
  int* best_g = (int*)(ws + off);      off += TT * sizeof(int);
  int* list = (int*)(ws + off);        off += (size_t)NE * TT * sizeof(int);
  int* cnt = (int*)(ws + off);         off += 16 * sizeof(int);
  int* meta = (int*)(ws + off);        off += 64 * sizeof(int);
  int* tokmap = (int*)(ws + off);

  hipMemsetAsync(d_out, 0, (size_t)out_size * sizeof(float), stream);
  guconv_router_kernel<<<dim3(GUCH + RBLK), dim3(256), 0, stream>>>(
      gate_w, up_w, sh_gate, sh_up, Wgt, Wut, x, rw, score, best_g);
  plan_kernel<<<dim3(1), dim3(256), 0, stream>>>(best_g, score, cnt, list, meta, out);
  gather_kernel<<<dim3(1920), dim3(256), 0, stream>>>(x, score, list, cnt, meta, Xc,
                                                      tokmap);
  stageA_dconv_kernel<<<dim3(SABLK + DCH), dim3(256), 0, stream>>>(
      Xc, meta, Wgt, Wut, P, down_w, sh_down, Wdt);
  stageB_kernel<<<dim3(6, 40, 2), dim3(256), 0, stream>>>(P, meta, tokmap, Wdt, out);
}

// Round 17
// 137.178 us; speedup vs baseline: 1.0310x; 1.0310x over previous
//
#include <hip/hip_runtime.h>
#include <hip/hip_bf16.h>

// MoE MLP top-1 + shared expert. T=2048 H=768 I=2048 E=8, f32 in/out.
// R17 = R15 (best, 137us) with stageB reverted to single-K (64 chunks) and
//       bumped to launch_bounds(256,4). Split-K (R16) regressed: 2x atomics.
//   K1: gate/up conv blocks + router tail (no global atomics).
//   plan: 1-block histogram/segments/list/loss (LDS atomics).
//   K2 = stageA + down conv fused; K3 = stageB. Layout (e,nt,kc).
// Chunk = 128 n x 32 k bf16 (4096 u16 = 8KB), in-chunk addr:
//   ((n>>4)&7)*512 + ((k>>3)&3)*128 + (n&15)*8 + (k&7)
// gll16 copies chunks linearly in the GEMMs; fragment reads linear-in-lane.

#define TT 2048
#define HH 768
#define II 2048
#define NE 8
#define RSLOTS 3072   // routed padded slots (24 tiles of 128)
#define LDSW 138      // wconv LDS row stride (u16)
#define GUCH 6912     // gate/up chunks (9 x {g,u} x 24 kc x 16 nt)
#define RBLK 512      // router blocks (tail of K1's grid)
#define SABLK 640     // stageA blocks (16 nt x 40 mty)
#define DCH 3456      // down chunks (9 x 64 kc x 6 nt)

typedef unsigned short u16;
typedef unsigned int u32;
typedef short s16x8 __attribute__((ext_vector_type(8)));
typedef u16 u16x8 __attribute__((ext_vector_type(8)));
typedef float f32x4 __attribute__((ext_vector_type(4)));

__device__ __forceinline__ u16 f2bf(float f) {  // f32 -> bf16 RNE
  u32 u = __builtin_bit_cast(u32, f);
  return (u16)((u + 0x7FFFu + ((u >> 16) & 1u)) >> 16);
}

typedef __attribute__((address_space(3))) u32 lds_u32;
typedef const __attribute__((address_space(1))) u32 glb_u32;
__device__ __forceinline__ void gll16(const void* g, void* l) {
  // global src per-lane; LDS dest wave-uniform base + lane*16 (linear)
  __builtin_amdgcn_global_load_lds((glb_u32*)g,
                                   (lds_u32*)(u32)(unsigned long long)l, 16, 0, 0);
}

// R5 one-shot conv body: [32k x 128n] f32 (row stride N) -> one tiled chunk.
__device__ __forceinline__ void conv_chunk(const float* src, int N, int k0, int n0,
                                           u16* dst, u16* lds, int t) {
  // phase 1: coalesced f32x4 reads along n; bf16 rows into LDS
  {
    const int k = t >> 3;         // 0..31
    const int nb = (t & 7) * 16;  // 16 consecutive n per thread
    const float* rp = src + (size_t)(k0 + k) * N + n0 + nb;
    const f32x4 a0 = *reinterpret_cast<const f32x4*>(rp);
    const f32x4 a1 = *reinterpret_cast<const f32x4*>(rp + 4);
    const f32x4 a2 = *reinterpret_cast<const f32x4*>(rp + 8);
    const f32x4 a3 = *reinterpret_cast<const f32x4*>(rp + 12);
    u16x8 w0, w1;
#pragma unroll
    for (int j = 0; j < 4; ++j) {
      w0[j] = f2bf(a0[j]); w0[j + 4] = f2bf(a1[j]);
      w1[j] = f2bf(a2[j]); w1[j + 4] = f2bf(a3[j]);
    }
    *reinterpret_cast<u16x8*>(&lds[k * LDSW + nb]) = w0;
    *reinterpret_cast<u16x8*>(&lds[k * LDSW + nb + 8]) = w1;
  }
  __syncthreads();
  // phase 2: k-minor gather from LDS, coalesced u16x8 stores
#pragma unroll
  for (int r = 0; r < 2; ++r) {
    const int o = t + r * 256;  // 0..511
    const int fr = o & 15, fq = (o >> 4) & 3, nq = o >> 6;
    u16x8 w;
#pragma unroll
    for (int j = 0; j < 8; ++j) w[j] = lds[(fq * 8 + j) * LDSW + nq * 16 + fr];
    *reinterpret_cast<u16x8*>(&dst[o * 8]) = w;
  }
}

// ---------------- K1: gate/up conversion + router (no atomics) ----------------
// blocks [0,GUCH): gu chunks, id: m=id/384 (e=m>>1, mat=m&1), r=id%384,
//   kc=r>>4, nt=r&15. dst (e,nt,kc): chunk ((e*16+nt)*24+kc).
// blocks [GUCH,GUCH+RBLK): router, one wave per token -> best[], score[].
__global__ __launch_bounds__(256) void guconv_router_kernel(
    const float* __restrict__ gate_w, const float* __restrict__ up_w,
    const float* __restrict__ sh_gate, const float* __restrict__ sh_up,
    u16* __restrict__ Wgt, u16* __restrict__ Wut,
    const float* __restrict__ x, const float* __restrict__ rw,
    float* __restrict__ score, int* __restrict__ best_g) {
  __shared__ u16 lds[32 * LDSW];  // 8.8 KB
  const int t = threadIdx.x;

  if (blockIdx.x >= GUCH) {
    // ---- router: one wave per token; plain stores only ----
    const int tok = (int)(((blockIdx.x - GUCH) * 256 + t) >> 6);
    const int lane = t & 63;
    if (tok >= TT) return;
    double acc[NE];
#pragma unroll
    for (int e = 0; e < NE; ++e) acc[e] = 0.0;
    const float* xr = x + (size_t)tok * HH;
    for (int h = lane; h < HH; h += 64) {
      const double xv = (double)xr[h];
#pragma unroll
      for (int e = 0; e < NE; ++e) acc[e] += xv * (double)rw[h * NE + e];
    }
#pragma unroll
    for (int off = 32; off > 0; off >>= 1) {
#pragma unroll
      for (int e = 0; e < NE; ++e) acc[e] += __shfl_xor(acc[e], off);
    }
    if (lane == 0) {
      int best = 0;
#pragma unroll
      for (int e = 1; e < NE; ++e)
        if (acc[e] > acc[best]) best = e;  // strict > == first-max (jnp.argmax)
      score[tok] = 1.0f / (1.0f + __expf((float)(-acc[best])));
      best_g[tok] = best;
    }
    return;
  }

  const int id = blockIdx.x;  // [0, GUCH)
  const int m = id / 384, r = id % 384;
  const int e = m >> 1;
  const int kc = r >> 4, nt = r & 15;
  const float* src = (m & 1) ? (e < 8 ? up_w + (size_t)e * HH * II : sh_up)
                             : (e < 8 ? gate_w + (size_t)e * HH * II : sh_gate);
  u16* dst = ((m & 1) ? Wut : Wgt) + ((size_t)(e * 16 + nt) * 24 + kc) * 4096;
  conv_chunk(src, II, kc * 32, nt * 128, dst, lds, t);
}

// ---------------- plan: histogram + segments + list + loss (1 block) ----------------
__global__ __launch_bounds__(256) void plan_kernel(
    const int* __restrict__ best_g, const float* __restrict__ score,
    int* __restrict__ cnt, int* __restrict__ list, int* __restrict__ meta,
    float* __restrict__ out) {
  __shared__ int hist[NE], cursor[NE];
  __shared__ float psum[NE];
  const int t = threadIdx.x;
  if (t < NE) {
    hist[t] = 0;
    cursor[t] = 0;
    psum[t] = 0.0f;
  }
  __syncthreads();
  // pass 1: histogram + prob sums (LDS atomics)
#pragma unroll
  for (int i = 0; i < TT / 256; ++i) {
    const int tok = t + i * 256;
    const int e = best_g[tok];
    atomicAdd(&hist[e], 1);
    atomicAdd(&psum[e], score[tok]);
  }
  __syncthreads();
  if (t == 0) {
    int S = 0;
    float s = 0.0f;
    for (int e = 0; e < NE; ++e) {
      cnt[e] = hist[e];
      meta[e] = S;
      const int pad = (hist[e] + 127) & ~127;
      for (int tl = S >> 7; tl < (S + pad) >> 7; ++tl) meta[16 + tl] = e;
      S += pad;
      s += (float)hist[e] * psum[e];
    }
    meta[8] = S;
    for (int tl = S >> 7; tl < 24; ++tl) meta[16 + tl] = 0;
    out[(size_t)TT * HH] = s * (0.001f * (float)NE / ((float)TT * (float)TT));
  }
  __syncthreads();
  // pass 2: compacted per-expert lists (LDS cursors; order irrelevant)
#pragma unroll
  for (int i = 0; i < TT / 256; ++i) {
    const int tok = t + i * 256;
    const int e = best_g[tok];
    const int pos = atomicAdd(&cursor[e], 1);
    list[e * TT + pos] = tok;
  }
}

// ---------------- gather: x -> tiled bf16 Xc (+tokmap) ----------------
__global__ __launch_bounds__(256) void gather_kernel(
    const float* __restrict__ x, const float* __restrict__ score,
    const int* __restrict__ list, const int* __restrict__ cnt,
    const int* __restrict__ meta, u16* __restrict__ Xc, int* __restrict__ tokmap) {
  const int task = blockIdx.x * 4 + (threadIdx.x >> 6);
  const int lane = threadIdx.x & 63;
  const int pb = task / 24;  // 16-row block, 0..319
  const int c = task % 24;   // k chunk
  const int fq = lane >> 4, fr = lane & 15;
  const int p = pb * 16 + fr;
  int tok;
  float sc;
  if (p >= RSLOTS) {
    tok = p - RSLOTS;
    sc = 1.0f;
  } else {
    const int e = meta[16 + (p >> 7)];
    const int idx = p - meta[e];
    tok = (idx >= 0 && idx < cnt[e]) ? list[e * TT + idx] : -1;
    sc = (tok >= 0) ? score[tok] : 0.0f;
  }
  u16x8 w = {0, 0, 0, 0, 0, 0, 0, 0};
  if (tok >= 0) {
    const float* xp = x + (size_t)tok * HH + c * 32 + fq * 8;
    const f32x4 a = *reinterpret_cast<const f32x4*>(xp);
    const f32x4 b = *reinterpret_cast<const f32x4*>(xp + 4);
#pragma unroll
    for (int j = 0; j < 4; ++j) {
      w[j] = f2bf(a[j] * sc);
      w[j + 4] = f2bf(b[j] * sc);
    }
  }
  *reinterpret_cast<u16x8*>(&Xc[((size_t)(pb >> 3) * 24 + c) * 4096 + (pb & 7) * 512 +
                                lane * 8]) = w;
  if (c == 0 && fq == 0) tokmap[p] = tok;
}

// ---------------- K2: stageA + down conversion fused ----------------
// blocks [0,SABLK): stageA (nt=b&15, mty=b>>4; mty<24 routed, >=24 shared).
// blocks [SABLK,SABLK+DCH): down chunks, id: e=id/384, r=id%384, kc=r/6, nt=r%6.
// dst (e,nt,kc): chunk ((e*6+nt)*64+kc). Wdt consumed by stageB.
__global__ __launch_bounds__(256, 3) void stageA_dconv_kernel(
    const u16* __restrict__ Xc, const int* __restrict__ meta,
    const u16* __restrict__ Wgt, const u16* __restrict__ Wut, u16* __restrict__ P,
    const float* __restrict__ down_w, const float* __restrict__ sh_down,
    u16* __restrict__ Wdt) {
  __shared__ char smem[49152];  // stageA: 48 KB; down conv: first 8.8 KB
  const int tid = threadIdx.x;

  if (blockIdx.x >= SABLK) {
    // ---- down conversion (R5 body) ----
    const int id = blockIdx.x - SABLK;  // [0, DCH)
    const int e = id / 384, r = id % 384;
    const int kc = r / 6, nt = r % 6;
    const float* src = (e < 8) ? down_w + (size_t)e * II * HH : sh_down;
    u16* dst = Wdt + ((size_t)(e * 6 + nt) * 64 + kc) * 4096;
    conv_chunk(src, HH, kc * 32, nt * 128, dst, (u16*)smem, tid);
    return;
  }

  // ---- stageA: P = silu(Xc Wg) * (Xc Wu) ----
  const int nt = blockIdx.x & 15, mty = blockIdx.x >> 4;
  int e;
  if (mty < 24) {
    if (mty * 128 >= meta[8]) return;
    e = meta[16 + mty];
  } else {
    e = 8;
  }
  const u16* wg = Wgt + (size_t)(e * 16 + nt) * 24 * 4096;
  const u16* wu = Wut + (size_t)(e * 16 + nt) * 24 * 4096;
  const u16* xa = Xc + (size_t)mty * 24 * 4096;

  u16(*As)[4096] = (u16(*)[4096])smem;
  u16(*Bgs)[4096] = (u16(*)[4096])(smem + 16384);
  u16(*Bus)[4096] = (u16(*)[4096])(smem + 32768);

  const int lane = tid & 63, wid = tid >> 6;
  const int fr = lane & 15, fq = lane >> 4;
  const int wm4 = (wid >> 1) * 4;  // row 16-block base
  const int wn4 = (wid & 1) * 4;   // col 16-block base
  const int wn = (wid & 1) * 64;
  const int ncol = nt * 128;
  const int so = wid * 1024 + lane * 8;  // gll global src offset (u16)
  const int sl = wid * 1024;             // gll LDS dst offset (u16), wave-uniform

  f32x4 accg[4][4], accu[4][4];
#pragma unroll
  for (int i = 0; i < 4; ++i)
#pragma unroll
    for (int j = 0; j < 4; ++j) {
      accg[i][j] = f32x4{0.f, 0.f, 0.f, 0.f};
      accu[i][j] = f32x4{0.f, 0.f, 0.f, 0.f};
    }

  // full chunk = 4096 u16; 4 waves x 2 gll16 x 512 u16 each
#define STAGE(c, buf)                                               \
  {                                                                 \
    gll16(xa + (size_t)(c) * 4096 + so, &As[buf][sl]);              \
    gll16(xa + (size_t)(c) * 4096 + so + 512, &As[buf][sl + 512]);  \
    gll16(wg + (size_t)(c) * 4096 + so, &Bgs[buf][sl]);             \
    gll16(wg + (size_t)(c) * 4096 + so + 512, &Bgs[buf][sl + 512]); \
    gll16(wu + (size_t)(c) * 4096 + so, &Bus[buf][sl]);             \
    gll16(wu + (size_t)(c) * 4096 + so + 512, &Bus[buf][sl + 512]); \
  }

  STAGE(0, 0)
  __syncthreads();
  int cur = 0;
  for (int c = 0; c < 24; ++c) {
    if (c < 23) STAGE(c + 1, cur ^ 1)
    s16x8 af[4], bg[4], bu[4];
#pragma unroll
    for (int i = 0; i < 4; ++i) {
      af[i] = *reinterpret_cast<const s16x8*>(&As[cur][(wm4 + i) * 512 + fq * 128 + fr * 8]);
      bg[i] = *reinterpret_cast<const s16x8*>(&Bgs[cur][(wn4 + i) * 512 + fq * 128 + fr * 8]);
      bu[i] = *reinterpret_cast<const s16x8*>(&Bus[cur][(wn4 + i) * 512 + fq * 128 + fr * 8]);
    }
#pragma unroll
    for (int j = 0; j < 4; ++j)
#pragma unroll
      for (int i = 0; i < 4; ++i) {
        accg[i][j] = __builtin_amdgcn_mfma_f32_16x16x32_bf16(af[i], bg[j], accg[i][j], 0, 0, 0);
        accu[i][j] = __builtin_amdgcn_mfma_f32_16x16x32_bf16(af[i], bu[j], accu[i][j], 0, 0, 0);
      }
    __syncthreads();
    cur ^= 1;
  }
#undef STAGE

  // epilogue: silu(g)*u -> P tiled bf16 (C/D: row=fq*4+reg, col=fr)
#pragma unroll
  for (int i = 0; i < 4; ++i)
#pragma unroll
    for (int cc = 0; cc < 4; ++cc) {
      const int rlo = fq * 4 + cc;  // row & 15 within 16-block (wm4+i)
#pragma unroll
      for (int j = 0; j < 4; ++j) {
        const int k = ncol + wn + j * 16 + fr;  // global i-col
        const float gv = accg[i][j][cc];
        const float val = (gv / (1.0f + __expf(-gv))) * accu[i][j][cc];
        P[((size_t)mty * 64 + (k >> 5)) * 4096 + (size_t)(wm4 + i) * 512 +
          ((k >> 3) & 3) * 128 + rlo * 8 + (k & 7)] = f2bf(val);
      }
    }
}

// ---------------- stage B: out += P Wd (atomicAdd, out pre-zeroed) ----------------
// grid (6 nt, 40 mty); each out element gets one shared + at most one routed add.
__global__ __launch_bounds__(256, 4) void stageB_kernel(
    const u16* __restrict__ P, const int* __restrict__ meta,
    const int* __restrict__ tokmap, const u16* __restrict__ Wdt,
    float* __restrict__ out) {
  const int mty = blockIdx.y, nt = blockIdx.x;
  int e;
  if (mty < 24) {
    if (mty * 128 >= meta[8]) return;
    e = meta[16 + mty];
  } else {
    e = 8;
  }
  const u16* wd = Wdt + (size_t)(e * 6 + nt) * 64 * 4096;
  const u16* pa = P + (size_t)mty * 64 * 4096;

  __shared__ u16 As[2][4096], Bs[2][4096];

  const int tid = threadIdx.x, lane = tid & 63, wid = tid >> 6;
  const int fr = lane & 15, fq = lane >> 4;
  const int wm4 = (wid >> 1) * 4;
  const int wn4 = (wid & 1) * 4;
  const int wm = (wid >> 1) * 64;
  const int wn = (wid & 1) * 64;
  const int ncol = nt * 128;
  const int so = wid * 1024 + lane * 8;
  const int sl = wid * 1024;

  f32x4 acc[4][4];
#pragma unroll
  for (int i = 0; i < 4; ++i)
#pragma unroll
    for (int j = 0; j < 4; ++j) acc[i][j] = f32x4{0.f, 0.f, 0.f, 0.f};

#define STAGEB(c, buf)                                              \
  {                                                                 \
    gll16(pa + (size_t)(c) * 4096 + so, &As[buf][sl]);              \
    gll16(pa + (size_t)(c) * 4096 + so + 512, &As[buf][sl + 512]);  \
    gll16(wd + (size_t)(c) * 4096 + so, &Bs[buf][sl]);              \
    gll16(wd + (size_t)(c) * 4096 + so + 512, &Bs[buf][sl + 512]);  \
  }

  STAGEB(0, 0)
  __syncthreads();
  int cur = 0;
  for (int c = 0; c < 64; ++c) {
    if (c < 63) STAGEB(c + 1, cur ^ 1)
    s16x8 af[4], bf[4];
#pragma unroll
    for (int i = 0; i < 4; ++i) {
      af[i] = *reinterpret_cast<const s16x8*>(&As[cur][(wm4 + i) * 512 + fq * 128 + fr * 8]);
      bf[i] = *reinterpret_cast<const s16x8*>(&Bs[cur][(wn4 + i) * 512 + fq * 128 + fr * 8]);
    }
#pragma unroll
    for (int j = 0; j < 4; ++j)
#pragma unroll
      for (int i = 0; i < 4; ++i)
        acc[i][j] = __builtin_amdgcn_mfma_f32_16x16x32_bf16(af[i], bf[j], acc[i][j], 0, 0, 0);
    __syncthreads();
    cur ^= 1;
  }
#undef STAGEB

#pragma unroll
  for (int i = 0; i < 4; ++i)
#pragma unroll
    for (int cc = 0; cc < 4; ++cc) {
      const int p = mty * 128 + wm + i * 16 + fq * 4 + cc;
      const int tok = tokmap[p];
      if (tok >= 0) {
#pragma unroll
        for (int j = 0; j < 4; ++j)
          atomicAdd(&out[(size_t)tok * HH + ncol + wn + j * 16 + fr], acc[i][j][cc]);
      }
    }
}

// ---------------- launcher ----------------
extern "C" void kernel_launch(void* const* d_in, const int* in_sizes, int n_in,
                              void* d_out, int out_size, void* d_ws, size_t ws_size,
                              hipStream_t stream) {
  (void)in_sizes; (void)n_in; (void)ws_size;
  const float* x = (const float*)d_in[0];
  const float* rw = (const float*)d_in[1];
  const float* gate_w = (const float*)d_in[2];
  const float* up_w = (const float*)d_in[3];
  const float* down_w = (const float*)d_in[4];
  const float* sh_gate = (const float*)d_in[5];
  const float* sh_up = (const float*)d_in[6];
  const float* sh_down = (const float*)d_in[7];
  float* out = (float*)d_out;

  char* ws = (char*)d_ws;
  size_t off = 0;
  u16* Xc = (u16*)(ws + off);  off += (size_t)(RSLOTS + TT) * HH * sizeof(u16);   // 7.9MB
  u16* P = (u16*)(ws + off);   off += (size_t)(RSLOTS + TT) * II * sizeof(u16);   // 21MB
  u16* Wgt = (u16*)(ws + off); off += (size_t)9 * 16 * 24 * 4096 * sizeof(u16);   // 28.3MB
  u16* Wut = (u16*)(ws + off); off += (size_t)9 * 16 * 24 * 4096 * sizeof(u16);   // 28.3MB
  u16* Wdt = (u16*)(ws + off); off += (size_t)9 * 6 * 64 * 4096 * sizeof(u16);    // 28.3MB
  float* score = (float*)(ws + off);   off += TT * sizeof(float);
  int* best_g = (int*)(ws + off);      off += TT * sizeof(int);
  int* list = (int*)(ws + off);        off += (size_t)NE * TT * sizeof(int);
  int* cnt = (int*)(ws + off);         off += 16 * sizeof(int);
  int* meta = (int*)(ws + off);        off += 64 * sizeof(int);
  int* tokmap = (int*)(ws + off);

  hipMemsetAsync(d_out, 0, (size_t)out_size * sizeof(float), stream);
  guconv_router_kernel<<<dim3(GUCH + RBLK), dim3(256), 0, stream>>>(
      gate_w, up_w, sh_gate, sh_up, Wgt, Wut, x, rw, score, best_g);
  plan_kernel<<<dim3(1), dim3(256), 0, stream>>>(best_g, score, cnt, list, meta, out);
  gather_kernel<<<dim3(1920), dim3(256), 0, stream>>>(x, score, list, cnt, meta, Xc,
                                                      tokmap);
  stageA_dconv_kernel<<<dim3(SABLK + DCH), dim3(256), 0, stream>>>(
      Xc, meta, Wgt, Wut, P, down_w, sh_down, Wdt);
  stageB_kernel<<<dim3(6, 40, 1), dim3(256), 0, stream>>>(P, meta, tokmap, Wdt, out);
}

// Round 18
// 131.034 us; speedup vs baseline: 1.0793x; 1.0469x over previous
//
#include <hip/hip_runtime.h>
#include <hip/hip_bf16.h>

// MoE MLP top-1 + shared expert. T=2048 H=768 I=2048 E=8, f32 in/out.
// R18 = R17 (tied best, 137us) with router blocks moved to the FRONT of K1's
//       grid: router latency hides under the conv stream instead of forming
//       a serial tail.
//   K1: router blocks [0,RBLK) + gate/up conv blocks [RBLK,RBLK+GUCH).
//   plan: 1-block histogram/segments/list/loss (LDS atomics).
//   K2 = stageA + down conv fused; K3 = stageB (single-K, atomic epilogue).
// Chunk = 128 n x 32 k bf16 (4096 u16 = 8KB), in-chunk addr:
//   ((n>>4)&7)*512 + ((k>>3)&3)*128 + (n&15)*8 + (k&7)
// gll16 copies chunks linearly in the GEMMs; fragment reads linear-in-lane.

#define TT 2048
#define HH 768
#define II 2048
#define NE 8
#define RSLOTS 3072   // routed padded slots (24 tiles of 128)
#define LDSW 138      // wconv LDS row stride (u16)
#define GUCH 6912     // gate/up chunks (9 x {g,u} x 24 kc x 16 nt)
#define RBLK 512      // router blocks (front of K1's grid)
#define SABLK 640     // stageA blocks (16 nt x 40 mty)
#define DCH 3456      // down chunks (9 x 64 kc x 6 nt)

typedef unsigned short u16;
typedef unsigned int u32;
typedef short s16x8 __attribute__((ext_vector_type(8)));
typedef u16 u16x8 __attribute__((ext_vector_type(8)));
typedef float f32x4 __attribute__((ext_vector_type(4)));

__device__ __forceinline__ u16 f2bf(float f) {  // f32 -> bf16 RNE
  u32 u = __builtin_bit_cast(u32, f);
  return (u16)((u + 0x7FFFu + ((u >> 16) & 1u)) >> 16);
}

typedef __attribute__((address_space(3))) u32 lds_u32;
typedef const __attribute__((address_space(1))) u32 glb_u32;
__device__ __forceinline__ void gll16(const void* g, void* l) {
  // global src per-lane; LDS dest wave-uniform base + lane*16 (linear)
  __builtin_amdgcn_global_load_lds((glb_u32*)g,
                                   (lds_u32*)(u32)(unsigned long long)l, 16, 0, 0);
}

// R5 one-shot conv body: [32k x 128n] f32 (row stride N) -> one tiled chunk.
__device__ __forceinline__ void conv_chunk(const float* src, int N, int k0, int n0,
                                           u16* dst, u16* lds, int t) {
  // phase 1: coalesced f32x4 reads along n; bf16 rows into LDS
  {
    const int k = t >> 3;         // 0..31
    const int nb = (t & 7) * 16;  // 16 consecutive n per thread
    const float* rp = src + (size_t)(k0 + k) * N + n0 + nb;
    const f32x4 a0 = *reinterpret_cast<const f32x4*>(rp);
    const f32x4 a1 = *reinterpret_cast<const f32x4*>(rp + 4);
    const f32x4 a2 = *reinterpret_cast<const f32x4*>(rp + 8);
    const f32x4 a3 = *reinterpret_cast<const f32x4*>(rp + 12);
    u16x8 w0, w1;
#pragma unroll
    for (int j = 0; j < 4; ++j) {
      w0[j] = f2bf(a0[j]); w0[j + 4] = f2bf(a1[j]);
      w1[j] = f2bf(a2[j]); w1[j + 4] = f2bf(a3[j]);
    }
    *reinterpret_cast<u16x8*>(&lds[k * LDSW + nb]) = w0;
    *reinterpret_cast<u16x8*>(&lds[k * LDSW + nb + 8]) = w1;
  }
  __syncthreads();
  // phase 2: k-minor gather from LDS, coalesced u16x8 stores
#pragma unroll
  for (int r = 0; r < 2; ++r) {
    const int o = t + r * 256;  // 0..511
    const int fr = o & 15, fq = (o >> 4) & 3, nq = o >> 6;
    u16x8 w;
#pragma unroll
    for (int j = 0; j < 8; ++j) w[j] = lds[(fq * 8 + j) * LDSW + nq * 16 + fr];
    *reinterpret_cast<u16x8*>(&dst[o * 8]) = w;
  }
}

// ---------------- K1: router (front) + gate/up conversion ----------------
// blocks [0,RBLK): router, one wave per token -> best[], score[] (no atomics).
// blocks [RBLK,RBLK+GUCH): gu chunks, id=blockIdx-RBLK: m=id/384 (e=m>>1,
//   mat=m&1), r=id%384, kc=r>>4, nt=r&15. dst (e,nt,kc): chunk ((e*16+nt)*24+kc).
__global__ __launch_bounds__(256) void guconv_router_kernel(
    const float* __restrict__ gate_w, const float* __restrict__ up_w,
    const float* __restrict__ sh_gate, const float* __restrict__ sh_up,
    u16* __restrict__ Wgt, u16* __restrict__ Wut,
    const float* __restrict__ x, const float* __restrict__ rw,
    float* __restrict__ score, int* __restrict__ best_g) {
  __shared__ u16 lds[32 * LDSW];  // 8.8 KB
  const int t = threadIdx.x;

  if (blockIdx.x < RBLK) {
    // ---- router: one wave per token; plain stores only ----
    const int tok = (int)((blockIdx.x * 256 + t) >> 6);
    const int lane = t & 63;
    if (tok >= TT) return;
    double acc[NE];
#pragma unroll
    for (int e = 0; e < NE; ++e) acc[e] = 0.0;
    const float* xr = x + (size_t)tok * HH;
    for (int h = lane; h < HH; h += 64) {
      const double xv = (double)xr[h];
#pragma unroll
      for (int e = 0; e < NE; ++e) acc[e] += xv * (double)rw[h * NE + e];
    }
#pragma unroll
    for (int off = 32; off > 0; off >>= 1) {
#pragma unroll
      for (int e = 0; e < NE; ++e) acc[e] += __shfl_xor(acc[e], off);
    }
    if (lane == 0) {
      int best = 0;
#pragma unroll
      for (int e = 1; e < NE; ++e)
        if (acc[e] > acc[best]) best = e;  // strict > == first-max (jnp.argmax)
      score[tok] = 1.0f / (1.0f + __expf((float)(-acc[best])));
      best_g[tok] = best;
    }
    return;
  }

  const int id = blockIdx.x - RBLK;  // [0, GUCH)
  const int m = id / 384, r = id % 384;
  const int e = m >> 1;
  const int kc = r >> 4, nt = r & 15;
  const float* src = (m & 1) ? (e < 8 ? up_w + (size_t)e * HH * II : sh_up)
                             : (e < 8 ? gate_w + (size_t)e * HH * II : sh_gate);
  u16* dst = ((m & 1) ? Wut : Wgt) + ((size_t)(e * 16 + nt) * 24 + kc) * 4096;
  conv_chunk(src, II, kc * 32, nt * 128, dst, lds, t);
}

// ---------------- plan: histogram + segments + list + loss (1 block) ----------------
__global__ __launch_bounds__(256) void plan_kernel(
    const int* __restrict__ best_g, const float* __restrict__ score,
    int* __restrict__ cnt, int* __restrict__ list, int* __restrict__ meta,
    float* __restrict__ out) {
  __shared__ int hist[NE], cursor[NE];
  __shared__ float psum[NE];
  const int t = threadIdx.x;
  if (t < NE) {
    hist[t] = 0;
    cursor[t] = 0;
    psum[t] = 0.0f;
  }
  __syncthreads();
  // pass 1: histogram + prob sums (LDS atomics)
#pragma unroll
  for (int i = 0; i < TT / 256; ++i) {
    const int tok = t + i * 256;
    const int e = best_g[tok];
    atomicAdd(&hist[e], 1);
    atomicAdd(&psum[e], score[tok]);
  }
  __syncthreads();
  if (t == 0) {
    int S = 0;
    float s = 0.0f;
    for (int e = 0; e < NE; ++e) {
      cnt[e] = hist[e];
      meta[e] = S;
      const int pad = (hist[e] + 127) & ~127;
      for (int tl = S >> 7; tl < (S + pad) >> 7; ++tl) meta[16 + tl] = e;
      S += pad;
      s += (float)hist[e] * psum[e];
    }
    meta[8] = S;
    for (int tl = S >> 7; tl < 24; ++tl) meta[16 + tl] = 0;
    out[(size_t)TT * HH] = s * (0.001f * (float)NE / ((float)TT * (float)TT));
  }
  __syncthreads();
  // pass 2: compacted per-expert lists (LDS cursors; order irrelevant)
#pragma unroll
  for (int i = 0; i < TT / 256; ++i) {
    const int tok = t + i * 256;
    const int e = best_g[tok];
    const int pos = atomicAdd(&cursor[e], 1);
    list[e * TT + pos] = tok;
  }
}

// ---------------- gather: x -> tiled bf16 Xc (+tokmap) ----------------
__global__ __launch_bounds__(256) void gather_kernel(
    const float* __restrict__ x, const float* __restrict__ score,
    const int* __restrict__ list, const int* __restrict__ cnt,
    const int* __restrict__ meta, u16* __restrict__ Xc, int* __restrict__ tokmap) {
  const int task = blockIdx.x * 4 + (threadIdx.x >> 6);
  const int lane = threadIdx.x & 63;
  const int pb = task / 24;  // 16-row block, 0..319
  const int c = task % 24;   // k chunk
  const int fq = lane >> 4, fr = lane & 15;
  const int p = pb * 16 + fr;
  int tok;
  float sc;
  if (p >= RSLOTS) {
    tok = p - RSLOTS;
    sc = 1.0f;
  } else {
    const int e = meta[16 + (p >> 7)];
    const int idx = p - meta[e];
    tok = (idx >= 0 && idx < cnt[e]) ? list[e * TT + idx] : -1;
    sc = (tok >= 0) ? score[tok] : 0.0f;
  }
  u16x8 w = {0, 0, 0, 0, 0, 0, 0, 0};
  if (tok >= 0) {
    const float* xp = x + (size_t)tok * HH + c * 32 + fq * 8;
    const f32x4 a = *reinterpret_cast<const f32x4*>(xp);
    const f32x4 b = *reinterpret_cast<const f32x4*>(xp + 4);
#pragma unroll
    for (int j = 0; j < 4; ++j) {
      w[j] = f2bf(a[j] * sc);
      w[j + 4] = f2bf(b[j] * sc);
    }
  }
  *reinterpret_cast<u16x8*>(&Xc[((size_t)(pb >> 3) * 24 + c) * 4096 + (pb & 7) * 512 +
                                lane * 8]) = w;
  if (c == 0 && fq == 0) tokmap[p] = tok;
}

// ---------------- K2: stageA + down conversion fused ----------------
// blocks [0,SABLK): stageA (nt=b&15, mty=b>>4; mty<24 routed, >=24 shared).
// blocks [SABLK,SABLK+DCH): down chunks, id: e=id/384, r=id%384, kc=r/6, nt=r%6.
// dst (e,nt,kc): chunk ((e*6+nt)*64+kc). Wdt consumed by stageB.
__global__ __launch_bounds__(256, 3) void stageA_dconv_kernel(
    const u16* __restrict__ Xc, const int* __restrict__ meta,
    const u16* __restrict__ Wgt, const u16* __restrict__ Wut, u16* __restrict__ P,
    const float* __restrict__ down_w, const float* __restrict__ sh_down,
    u16* __restrict__ Wdt) {
  __shared__ char smem[49152];  // stageA: 48 KB; down conv: first 8.8 KB
  const int tid = threadIdx.x;

  if (blockIdx.x >= SABLK) {
    // ---- down conversion (R5 body) ----
    const int id = blockIdx.x - SABLK;  // [0, DCH)
    const int e = id / 384, r = id % 384;
    const int kc = r / 6, nt = r % 6;
    const float* src = (e < 8) ? down_w + (size_t)e * II * HH : sh_down;
    u16* dst = Wdt + ((size_t)(e * 6 + nt) * 64 + kc) * 4096;
    conv_chunk(src, HH, kc * 32, nt * 128, dst, (u16*)smem, tid);
    return;
  }

  // ---- stageA: P = silu(Xc Wg) * (Xc Wu) ----
  const int nt = blockIdx.x & 15, mty = blockIdx.x >> 4;
  int e;
  if (mty < 24) {
    if (mty * 128 >= meta[8]) return;
    e = meta[16 + mty];
  } else {
    e = 8;
  }
  const u16* wg = Wgt + (size_t)(e * 16 + nt) * 24 * 4096;
  const u16* wu = Wut + (size_t)(e * 16 + nt) * 24 * 4096;
  const u16* xa = Xc + (size_t)mty * 24 * 4096;

  u16(*As)[4096] = (u16(*)[4096])smem;
  u16(*Bgs)[4096] = (u16(*)[4096])(smem + 16384);
  u16(*Bus)[4096] = (u16(*)[4096])(smem + 32768);

  const int lane = tid & 63, wid = tid >> 6;
  const int fr = lane & 15, fq = lane >> 4;
  const int wm4 = (wid >> 1) * 4;  // row 16-block base
  const int wn4 = (wid & 1) * 4;   // col 16-block base
  const int wn = (wid & 1) * 64;
  const int ncol = nt * 128;
  const int so = wid * 1024 + lane * 8;  // gll global src offset (u16)
  const int sl = wid * 1024;             // gll LDS dst offset (u16), wave-uniform

  f32x4 accg[4][4], accu[4][4];
#pragma unroll
  for (int i = 0; i < 4; ++i)
#pragma unroll
    for (int j = 0; j < 4; ++j) {
      accg[i][j] = f32x4{0.f, 0.f, 0.f, 0.f};
      accu[i][j] = f32x4{0.f, 0.f, 0.f, 0.f};
    }

  // full chunk = 4096 u16; 4 waves x 2 gll16 x 512 u16 each
#define STAGE(c, buf)                                               \
  {                                                                 \
    gll16(xa + (size_t)(c) * 4096 + so, &As[buf][sl]);              \
    gll16(xa + (size_t)(c) * 4096 + so + 512, &As[buf][sl + 512]);  \
    gll16(wg + (size_t)(c) * 4096 + so, &Bgs[buf][sl]);             \
    gll16(wg + (size_t)(c) * 4096 + so + 512, &Bgs[buf][sl + 512]); \
    gll16(wu + (size_t)(c) * 4096 + so, &Bus[buf][sl]);             \
    gll16(wu + (size_t)(c) * 4096 + so + 512, &Bus[buf][sl + 512]); \
  }

  STAGE(0, 0)
  __syncthreads();
  int cur = 0;
  for (int c = 0; c < 24; ++c) {
    if (c < 23) STAGE(c + 1, cur ^ 1)
    s16x8 af[4], bg[4], bu[4];
#pragma unroll
    for (int i = 0; i < 4; ++i) {
      af[i] = *reinterpret_cast<const s16x8*>(&As[cur][(wm4 + i) * 512 + fq * 128 + fr * 8]);
      bg[i] = *reinterpret_cast<const s16x8*>(&Bgs[cur][(wn4 + i) * 512 + fq * 128 + fr * 8]);
      bu[i] = *reinterpret_cast<const s16x8*>(&Bus[cur][(wn4 + i) * 512 + fq * 128 + fr * 8]);
    }
#pragma unroll
    for (int j = 0; j < 4; ++j)
#pragma unroll
      for (int i = 0; i < 4; ++i) {
        accg[i][j] = __builtin_amdgcn_mfma_f32_16x16x32_bf16(af[i], bg[j], accg[i][j], 0, 0, 0);
        accu[i][j] = __builtin_amdgcn_mfma_f32_16x16x32_bf16(af[i], bu[j], accu[i][j], 0, 0, 0);
      }
    __syncthreads();
    cur ^= 1;
  }
#undef STAGE

  // epilogue: silu(g)*u -> P tiled bf16 (C/D: row=fq*4+reg, col=fr)
#pragma unroll
  for (int i = 0; i < 4; ++i)
#pragma unroll
    for (int cc = 0; cc < 4; ++cc) {
      const int rlo = fq * 4 + cc;  // row & 15 within 16-block (wm4+i)
#pragma unroll
      for (int j = 0; j < 4; ++j) {
        const int k = ncol + wn + j * 16 + fr;  // global i-col
        const float gv = accg[i][j][cc];
        const float val = (gv / (1.0f + __expf(-gv))) * accu[i][j][cc];
        P[((size_t)mty * 64 + (k >> 5)) * 4096 + (size_t)(wm4 + i) * 512 +
          ((k >> 3) & 3) * 128 + rlo * 8 + (k & 7)] = f2bf(val);
      }
    }
}

// ---------------- stage B: out += P Wd (atomicAdd, out pre-zeroed) ----------------
// grid (6 nt, 40 mty); each out element gets one shared + at most one routed add.
__global__ __launch_bounds__(256, 4) void stageB_kernel(
    const u16* __restrict__ P, const int* __restrict__ meta,
    const int* __restrict__ tokmap, const u16* __restrict__ Wdt,
    float* __restrict__ out) {
  const int mty = blockIdx.y, nt = blockIdx.x;
  int e;
  if (mty < 24) {
    if (mty * 128 >= meta[8]) return;
    e = meta[16 + mty];
  } else {
    e = 8;
  }
  const u16* wd = Wdt + (size_t)(e * 6 + nt) * 64 * 4096;
  const u16* pa = P + (size_t)mty * 64 * 4096;

  __shared__ u16 As[2][4096], Bs[2][4096];

  const int tid = threadIdx.x, lane = tid & 63, wid = tid >> 6;
  const int fr = lane & 15, fq = lane >> 4;
  const int wm4 = (wid >> 1) * 4;
  const int wn4 = (wid & 1) * 4;
  const int wm = (wid >> 1) * 64;
  const int wn = (wid & 1) * 64;
  const int ncol = nt * 128;
  const int so = wid * 1024 + lane * 8;
  const int sl = wid * 1024;

  f32x4 acc[4][4];
#pragma unroll
  for (int i = 0; i < 4; ++i)
#pragma unroll
    for (int j = 0; j < 4; ++j) acc[i][j] = f32x4{0.f, 0.f, 0.f, 0.f};

#define STAGEB(c, buf)                                              \
  {                                                                 \
    gll16(pa + (size_t)(c) * 4096 + so, &As[buf][sl]);              \
    gll16(pa + (size_t)(c) * 4096 + so + 512, &As[buf][sl + 512]);  \
    gll16(wd + (size_t)(c) * 4096 + so, &Bs[buf][sl]);              \
    gll16(wd + (size_t)(c) * 4096 + so + 512, &Bs[buf][sl + 512]);  \
  }

  STAGEB(0, 0)
  __syncthreads();
  int cur = 0;
  for (int c = 0; c < 64; ++c) {
    if (c < 63) STAGEB(c + 1, cur ^ 1)
    s16x8 af[4], bf[4];
#pragma unroll
    for (int i = 0; i < 4; ++i) {
      af[i] = *reinterpret_cast<const s16x8*>(&As[cur][(wm4 + i) * 512 + fq * 128 + fr * 8]);
      bf[i] = *reinterpret_cast<const s16x8*>(&Bs[cur][(wn4 + i) * 512 + fq * 128 + fr * 8]);
    }
#pragma unroll
    for (int j = 0; j < 4; ++j)
#pragma unroll
      for (int i = 0; i < 4; ++i)
        acc[i][j] = __builtin_amdgcn_mfma_f32_16x16x32_bf16(af[i], bf[j], acc[i][j], 0, 0, 0);
    __syncthreads();
    cur ^= 1;
  }
#undef STAGEB

#pragma unroll
  for (int i = 0; i < 4; ++i)
#pragma unroll
    for (int cc = 0; cc < 4; ++cc) {
      const int p = mty * 128 + wm + i * 16 + fq * 4 + cc;
      const int tok = tokmap[p];
      if (tok >= 0) {
#pragma unroll
        for (int j = 0; j < 4; ++j)
          atomicAdd(&out[(size_t)tok * HH + ncol + wn + j * 16 + fr], acc[i][j][cc]);
      }
    }
}

// ---------------- launcher ----------------
extern "C" void kernel_launch(void* const* d_in, const int* in_sizes, int n_in,
                              void* d_out, int out_size, void* d_ws, size_t ws_size,
                              hipStream_t stream) {
  (void)in_sizes; (void)n_in; (void)ws_size;
  const float* x = (const float*)d_in[0];
  const float* rw = (const float*)d_in[1];
  const float* gate_w = (const float*)d_in[2];
  const float* up_w = (const float*)d_in[3];
  const float* down_w = (const float*)d_in[4];
  const float* sh_gate = (const float*)d_in[5];
  const float* sh_up = (const float*)d_in[6];
  const float* sh_down = (const float*)d_in[7];
  float* out = (float*)d_out;

  char* ws = (char*)d_ws;
  size_t off = 0;
  u16* Xc = (u16*)(ws + off);  off += (size_t)(RSLOTS + TT) * HH * sizeof(u16);   // 7.9MB
  u16* P = (u16*)(ws + off);   off += (size_t)(RSLOTS + TT) * II * sizeof(u16);   // 21MB
  u16* Wgt = (u16*)(ws + off); off += (size_t)9 * 16 * 24 * 4096 * sizeof(u16);   // 28.3MB
  u16* Wut = (u16*)(ws + off); off += (size_t)9 * 16 * 24 * 4096 * sizeof(u16);   // 28.3MB
  u16* Wdt = (u16*)(ws + off); off += (size_t)9 * 6 * 64 * 4096 * sizeof(u16);    // 28.3MB
  float* score = (float*)(ws + off);   off += TT * sizeof(float);
  int* best_g = (int*)(ws + off);      off += TT * sizeof(int);
  int* list = (int*)(ws + off);        off += (size_t)NE * TT * sizeof(int);
  int* cnt = (int*)(ws + off);         off += 16 * sizeof(int);
  int* meta = (int*)(ws + off);        off += 64 * sizeof(int);
  int* tokmap = (int*)(ws + off);

  hipMemsetAsync(d_out, 0, (size_t)out_size * sizeof(float), stream);
  guconv_router_kernel<<<dim3(RBLK + GUCH), dim3(256), 0, stream>>>(
      gate_w, up_w, sh_gate, sh_up, Wgt, Wut, x, rw, score, best_g);
  plan_kernel<<<dim3(1), dim3(256), 0, stream>>>(best_g, score, cnt, list, meta, out);
  gather_kernel<<<dim3(1920), dim3(256), 0, stream>>>(x, score, list, cnt, meta, Xc,
                                                      tokmap);
  stageA_dconv_kernel<<<dim3(SABLK + DCH), dim3(256), 0, stream>>>(
      Xc, meta, Wgt, Wut, P, down_w, sh_down, Wdt);
  stageB_kernel<<<dim3(6, 40, 1), dim3(256), 0, stream>>>(P, meta, tokmap, Wdt, out);
}